// Round 9
// baseline (107.181 us; speedup 1.0000x reference)
//
#include <hip/hip_runtime.h>

#define BB 32
#define NP 2048
#define NG 2048
#define EPSF 1e-6f
#define BIGF 1e18f
#define FLTMAX 3.4e38f
#define MT 128   // m-tile staged in LDS per block
#define MP 16    // partials per side
#define TPT 4    // points per thread (R6 best-measured config)

typedef float v2f __attribute__((ext_vector_type(2)));

// ws layout (all regions fully overwritten every call -> no init memsets):
//  [0, 8448)            : fpart[264][8] floats (k_fin per-block partial sums)
//  [65536, +8MB)        : pred partials u64 [b][mp][n]  (dist_bits<<32 | idx)
//  [65536+8MB, +4MB)    : tgt partials f32 [b][np][m]
#define FPART_OFF 0
#define PPART_OFF 65536
#define TPART_OFF (65536 + BB * MP * NP * 8)

// Fused pairwise kernel. Blocks [0,1024): pred side (masked min+argmin over
// targets); blocks [1024,2048): tgt side (unmasked min over preds).
// Per side: 32 b * 2 nch * 16 mp; thread owns 4 points; 128 opposite-side
// points in LDS. Inner loop processes m,m+1 as float2 so the backend emits
// v_pk_fma_f32 / v_pk_min_f32 (2 fp32 ops per instr) — k_pair is
// instruction-ISSUE-bound (R8 budget: ~35us vs 17us scalar-issue floor),
// so packed math cuts the dominant cost.
// NOTE (R7 lesson): do NOT fuse stages with device fences — each
// __threadfence() on gfx950 is an L2 writeback+invalidate; kernel
// boundaries flush once.
__global__ __launch_bounds__(256, 8) void k_pair(const float* __restrict__ preds,
                                                 const float* __restrict__ target,
                                                 const float* __restrict__ mask,
                                                 unsigned long long* __restrict__ ppart,
                                                 float* __restrict__ tpart) {
  __shared__ float4 s4[MT];
  const int bx = blockIdx.x;
  const int tid = threadIdx.x;

  if (bx < 1024) {
    // ---- pred side ----
    const int b = bx >> 5;
    const int nch = (bx >> 4) & 1;
    const int mp = bx & 15;
    const float* tb = target + b * 4 * NG;
    const int mbase = mp * MT;
    if (tid < MT) {
      int m = mbase + tid;
      float tx = tb[m], ty = tb[NG + m], tz = tb[2 * NG + m];
      float tn = fmaf(tx, tx, fmaf(ty, ty, tz * tz));
      float w = tn + (mask[b * NG + m] == 0.0f ? BIGF : 0.0f);  // fold BIG mask
      s4[tid] = make_float4(-2.0f * tx, -2.0f * ty, -2.0f * tz, w);
    }
    __syncthreads();

    const float* pb = preds + b * 5 * NP;
    const int nbase = nch * 1024 + tid;
    float px[TPT], py[TPT], pz[TPT], bv[TPT];
    int bi[TPT];
#pragma unroll
    for (int k = 0; k < TPT; k++) {
      int n = nbase + k * 256;
      px[k] = pb[n];
      py[k] = pb[NP + n];
      pz[k] = pb[2 * NP + n];
      bv[k] = FLTMAX;
      bi[k] = 0;
    }

    // s = tn - 2*dot (+BIG if masked); pn^2 thread-invariant -> folded out.
#pragma unroll 2
    for (int m = 0; m < MT; m += 2) {
      float4 t = s4[m];
      float4 u = s4[m + 1];
      v2f xs = {t.x, u.x}, ys = {t.y, u.y}, zs = {t.z, u.z}, ws = {t.w, u.w};
#pragma unroll
      for (int k = 0; k < TPT; k++) {
        v2f pxk = {px[k], px[k]}, pyk = {py[k], py[k]}, pzk = {pz[k], pz[k]};
        v2f s2 = __builtin_elementwise_fma(
            pxk, xs, __builtin_elementwise_fma(pyk, ys,
                       __builtin_elementwise_fma(pzk, zs, ws)));
        // even first, then odd, strict < : preserves first-index tie-break
        if (s2.x < bv[k]) { bv[k] = s2.x; bi[k] = m; }
        if (s2.y < bv[k]) { bv[k] = s2.y; bi[k] = m + 1; }
      }
    }

    unsigned long long* row = &ppart[(b * MP + mp) * NP];
#pragma unroll
    for (int k = 0; k < TPT; k++) {
      float pn = fmaf(px[k], px[k], fmaf(py[k], py[k], pz[k] * pz[k]));
      float d = fmaxf(bv[k] + pn, 0.0f);
      row[nbase + k * 256] =
          ((unsigned long long)__float_as_uint(d) << 32) | (unsigned)(mbase + bi[k]);
    }
  } else {
    // ---- tgt side ----
    const int bb = bx - 1024;
    const int b = bb >> 5;
    const int mch = (bb >> 4) & 1;
    const int np_ = bb & 15;
    const float* pb = preds + b * 5 * NP;
    if (tid < MT) {
      int n = np_ * MT + tid;
      float px = pb[n], py = pb[NP + n], pz = pb[2 * NP + n];
      float pn2 = fmaf(px, px, fmaf(py, py, pz * pz));
      s4[tid] = make_float4(-2.0f * px, -2.0f * py, -2.0f * pz, pn2);
    }
    __syncthreads();

    const float* tb = target + b * 4 * NG;
    const int mbase2 = mch * 1024 + tid;
    float tx[TPT], ty[TPT], tz[TPT];
    v2f cv[TPT];
#pragma unroll
    for (int k = 0; k < TPT; k++) {
      int m = mbase2 + k * 256;
      tx[k] = tb[m];
      ty[k] = tb[NG + m];
      tz[k] = tb[2 * NG + m];
      cv[k] = (v2f){FLTMAX, FLTMAX};
    }

#pragma unroll 2
    for (int n = 0; n < MT; n += 2) {
      float4 p = s4[n];
      float4 q = s4[n + 1];
      v2f xs = {p.x, q.x}, ys = {p.y, q.y}, zs = {p.z, q.z}, ws = {p.w, q.w};
#pragma unroll
      for (int k = 0; k < TPT; k++) {
        v2f txk = {tx[k], tx[k]}, tyk = {ty[k], ty[k]}, tzk = {tz[k], tz[k]};
        v2f s2 = __builtin_elementwise_fma(
            txk, xs, __builtin_elementwise_fma(tyk, ys,
                       __builtin_elementwise_fma(tzk, zs, ws)));
        cv[k] = __builtin_elementwise_min(cv[k], s2);  // v_pk_min_f32
      }
    }

    float* row = &tpart[(b * MP + np_) * NG];
#pragma unroll
    for (int k = 0; k < TPT; k++) {
      float tn = fmaf(tx[k], tx[k], fmaf(ty[k], ty[k], tz[k] * tz[k]));
      row[mbase2 + k * 256] = fmaxf(fminf(cv[k].x, cv[k].y) + tn, 0.0f);
    }
  }
}

// Combine: blocks [0,128) pred side, [128,256) tgt side, [256,264) kld.
// Reduces 16 partials per point, computes elementwise pieces, block-level
// LDS reduction, writes 5 partial sums to a private slot (no atomics).
__global__ __launch_bounds__(256) void k_fin(const unsigned long long* __restrict__ ppart,
                                             const float* __restrict__ tpart,
                                             const float* __restrict__ preds,
                                             const float* __restrict__ target,
                                             const float* __restrict__ mask,
                                             const float* __restrict__ mu,
                                             const float* __restrict__ logvar,
                                             float* __restrict__ fpart) {
  __shared__ float red[4][8];
  const int bx = blockIdx.x;
  const int tid = threadIdx.x;
  const int wave = tid >> 6, lane = tid & 63;
  float q0 = 0.0f, q1 = 0.0f, q2 = 0.0f, q3 = 0.0f, q4 = 0.0f;

  if (bx < 128) {
    const int b = bx >> 2;
    const float* pb = preds + b * 5 * NP;
    const float* te = target + b * 4 * NG + 3 * NG;
#pragma unroll
    for (int e = 0; e < 2; e++) {
      int i = bx * 512 + e * 256 + tid;
      int n = i & 2047;
      unsigned long long best = 0xFFFFFFFFFFFFFFFFull;
      const unsigned long long* col = &ppart[b * MP * NP + n];
#pragma unroll
      for (int mp = 0; mp < MP; mp++) {
        unsigned long long v = col[mp * NP];  // coalesced across lanes
        best = v < best ? v : best;           // min packed: dist then index
      }
      float bd = __uint_as_float((unsigned)(best >> 32));
      int idx = (int)(best & 0xffffffffu);
      float mE = te[idx];
      float pE = pb[3 * NP + n];
      float ph = pb[4 * NP + n];
      q0 += bd;
      q1 += fabsf(pE - mE);
      q2 += ph * logf(ph + EPSF) + (1.0f - ph) * logf(1.0f - ph + EPSF);
      q3 += ph;
      q4 += pE * ph;
    }
  } else if (bx < 256) {
    const int bb = bx - 128;
    const int b = bb >> 2;
#pragma unroll
    for (int e = 0; e < 2; e++) {
      int i = bb * 512 + e * 256 + tid;
      int m = i & 2047;
      float d = FLTMAX;
      const float* col = &tpart[b * MP * NG + m];
#pragma unroll
      for (int np_ = 0; np_ < MP; np_++) d = fminf(d, col[np_ * NG]);
      float msk = mask[i];
      q0 += d * msk;  // sum min_dist_tgt * mask
      q1 += msk;      // global mask sum
      q2 += msk;      // per-b mask sum (same value, separate slot)
    }
  } else {
    const int bb = bx - 256;  // B*L = 8192 over 8 blocks
#pragma unroll
    for (int e = 0; e < 4; e++) {
      int i = bb * 1024 + e * 256 + tid;
      float m = mu[i], lv = logvar[i];
      q0 += 1.0f + lv - m * m - expf(lv);
    }
  }

  float qs[5] = {q0, q1, q2, q3, q4};
  for (int k = 0; k < 5; k++) {
    float v = qs[k];
    v += __shfl_down(v, 32);
    v += __shfl_down(v, 16);
    v += __shfl_down(v, 8);
    v += __shfl_down(v, 4);
    v += __shfl_down(v, 2);
    v += __shfl_down(v, 1);
    if (lane == 0) red[wave][k] = v;
  }
  __syncthreads();
  if (tid < 5) fpart[bx * 8 + tid] = red[0][tid] + red[1][tid] + red[2][tid] + red[3][tid];
}

// Single-block final reduction over fpart rows + loss assembly.
__global__ __launch_bounds__(256) void k_final(const float* __restrict__ fpart,
                                               const float* __restrict__ e_init,
                                               const float* __restrict__ kl_weight,
                                               float* __restrict__ out) {
  __shared__ float red[4][8];
  const int t = threadIdx.x;
  const int wave = t >> 6, lane = t & 63;
  float g[8] = {0, 0, 0, 0, 0, 0, 0, 0};
  // g0 sum_min_pred, g1 sum|dE|, g2 entropy, g3 sum d*msk, g4 mask_sum,
  // g5 kld_sum, g6 hit_sq_sum, g7 esq_sum
  if (t < 128) {
    const float* r = &fpart[t * 8];
    g[0] = r[0]; g[1] = r[1]; g[2] = r[2];
    const float* r2 = &fpart[(128 + t) * 8];
    g[3] = r2[0]; g[4] = r2[1];
  }
  if (t < 8) g[5] = fpart[(256 + t) * 8];
  if (t < BB) {
    float hit = 0.0f, eh = 0.0f, mk = 0.0f;
#pragma unroll
    for (int k = 0; k < 4; k++) {
      hit += fpart[(4 * t + k) * 8 + 3];
      eh += fpart[(4 * t + k) * 8 + 4];
      mk += fpart[(128 + 4 * t + k) * 8 + 2];
    }
    float dh = hit - mk;
    g[6] = dh * dh;
    float de = eh - e_init[t];
    g[7] = de * de;
  }
  for (int k = 0; k < 8; k++) {
    float v = g[k];
    v += __shfl_down(v, 32);
    v += __shfl_down(v, 16);
    v += __shfl_down(v, 8);
    v += __shfl_down(v, 4);
    v += __shfl_down(v, 2);
    v += __shfl_down(v, 1);
    if (lane == 0) red[wave][k] = v;
  }
  __syncthreads();
  if (t == 0) {
    float s[8];
    for (int k = 0; k < 8; k++) s[k] = red[0][k] + red[1][k] + red[2][k] + red[3][k];
    const float invBN = 1.0f / (float)(BB * NP);
    float chamfer_pred = s[0] * invBN;
    float localE = s[1] * invBN;
    float ent = -s[2] * invBN;
    float chamfer_tgt = s[3] / s[4];
    float kld = -0.5f * s[5] / (float)BB;
    float hit = s[6] / (float)BB;
    float ge = s[7] / (float)BB;

    float loss_chamf = (chamfer_tgt + chamfer_pred) * 0.001f;  // LAMBDA_CHAMFER
    float losskld = kl_weight[0] * kld;
    float loss_ge = 10.0f * ge;    // LAMBDA_E_SUM
    float loss_hit = 20.0f * hit;  // LAMBDA_HIT
    float loss_ent = 0.1f * ent;   // LAMBDA_HIT_ENTROPY

    float total = loss_chamf + localE + losskld + loss_ge + loss_hit + loss_ent;
    out[0] = total;
    out[1] = loss_chamf;
    out[2] = localE;
    out[3] = loss_ge;
    out[4] = loss_hit;
    out[5] = losskld;
  }
}

extern "C" void kernel_launch(void* const* d_in, const int* in_sizes, int n_in,
                              void* d_out, int out_size, void* d_ws, size_t ws_size,
                              hipStream_t stream) {
  const float* preds = (const float*)d_in[0];
  const float* target = (const float*)d_in[1];
  const float* mask = (const float*)d_in[2];
  const float* mu = (const float*)d_in[3];
  const float* logvar = (const float*)d_in[4];
  const float* e_init = (const float*)d_in[5];
  const float* kl_weight = (const float*)d_in[6];
  float* fpart = (float*)((char*)d_ws + FPART_OFF);
  unsigned long long* ppart = (unsigned long long*)((char*)d_ws + PPART_OFF);
  float* tpart = (float*)((char*)d_ws + TPART_OFF);
  float* out = (float*)d_out;

  k_pair<<<2048, 256, 0, stream>>>(preds, target, mask, ppart, tpart);
  k_fin<<<264, 256, 0, stream>>>(ppart, tpart, preds, target, mask, mu, logvar, fpart);
  k_final<<<1, 256, 0, stream>>>(fpart, e_init, kl_weight, out);
}